// Round 9
// baseline (234.802 us; speedup 1.0000x reference)
//
#include <hip/hip_runtime.h>
#include <hip/hip_bf16.h>
#include <cstdint>
#include <cstddef>

#define N_NODES 50000
#define DEG     24
#define NEDGE   (N_NODES*DEG)
#define RSZ     500
#define NDIM    64
#define FEATD   192
#define NTILES  (N_NODES/16)     // 3125

// LDS row stride (shorts) for the 16x64 pa transpose buffer in k_gate.
#define PASTR   72

// k_layer grid: 32 nodes/block (8 lanes x 8 dims per node), 1563 logical blocks,
// padded to 1568 = 8*196 for the XCD swizzle.
#define LGRID   1568
#define LCHUNK  196

typedef short bf16x8 __attribute__((ext_vector_type(8)));
typedef float f32x4  __attribute__((ext_vector_type(4)));

__device__ __forceinline__ unsigned short f2bf(float f) {
    unsigned u = __builtin_bit_cast(unsigned, f);
    unsigned r = (u + 0x7fffu + ((u >> 16) & 1u)) >> 16;   // RNE
    return (unsigned short)r;
}
__device__ __forceinline__ float bf2f(unsigned short s) {
    unsigned u = ((unsigned)s) << 16;
    return __builtin_bit_cast(float, u);
}
__device__ __forceinline__ float lo16(unsigned u) {       // low bf16 of a dword
    return __builtin_bit_cast(float, u << 16);
}
__device__ __forceinline__ float hi16(unsigned u) {       // high bf16 of a dword
    return __builtin_bit_cast(float, u & 0xFFFF0000u);
}
__device__ __forceinline__ float fast_tanh(float x) {
    float e = __expf(2.f * x);
    return 1.f - 2.f / (e + 1.f);
}

// ---- PREP (fused): tanh(features)->fin0 (bf16) | l2norm(rel)+exp(attdot) |
//      1/||proxy_n|| | pack B1/B2/B3 | pack edges | B4 = proxy @ gate_w^T.
// Block ranges: [0,3125) tanh, [3125,3250) rel, [3250,3266) pninv,
//               [3266,3506) packB, [3506,4678) packE, [4678,4726) B4.
__global__ __launch_bounds__(256) void k_prep(const float* __restrict__ features,
                                              const float* __restrict__ rel_emb,
                                              const float* __restrict__ attn_k,
                                              const float* __restrict__ proxy,
                                              const float* __restrict__ gate_w,
                                              const int* __restrict__ src,
                                              const int* __restrict__ rel,
                                              unsigned short* __restrict__ fin0,
                                              float* __restrict__ reln,
                                              float* __restrict__ expdot,
                                              float* __restrict__ pninv,
                                              unsigned short* __restrict__ B1,
                                              unsigned short* __restrict__ B2,
                                              unsigned short* __restrict__ B3,
                                              unsigned short* __restrict__ B4,
                                              unsigned int* __restrict__ pedge) {
    int b = blockIdx.x;
    if (b < 3125) {
        int t = b * 256 + threadIdx.x;             // 800000 threads, 4 elems each
        int idx4 = t * 4;
        float4 f = *reinterpret_cast<const float4*>(features + idx4);
        uint2 w;
        w.x = (unsigned)f2bf(fast_tanh(f.x)) | ((unsigned)f2bf(fast_tanh(f.y)) << 16);
        w.y = (unsigned)f2bf(fast_tanh(f.z)) | ((unsigned)f2bf(fast_tanh(f.w)) << 16);
        *reinterpret_cast<uint2*>(fin0 + idx4) = w;
    } else if (b < 3250) {
        int lane = threadIdx.x & 63;
        int row = (b - 3125) * 4 + (threadIdx.x >> 6);   // 500 rows
        float v = rel_emb[row * 64 + lane];
        float ss = v * v;
        for (int m = 1; m < 64; m <<= 1) ss += __shfl_xor(ss, m);
        float inv = 1.f / fmaxf(sqrtf(ss), 1e-12f);
        float rn = v * inv;
        reln[row * 64 + lane] = rn;
        float d0 = rn * attn_k[lane];
        float d1 = rn * attn_k[64 + lane];
        for (int m = 1; m < 64; m <<= 1) { d0 += __shfl_xor(d0, m); d1 += __shfl_xor(d1, m); }
        if (lane == 0) { expdot[row] = __expf(d0); expdot[RSZ + row] = __expf(d1); }
    } else if (b < 3266) {
        int lane = threadIdx.x & 63;
        int row = (b - 3250) * 4 + (threadIdx.x >> 6);   // 64 rows
        const float* p = proxy + (size_t)row * FEATD;
        float a = p[lane], bb = p[64 + lane], c = p[128 + lane];
        float ss = a * a + bb * bb + c * c;
        for (int m = 1; m < 64; m <<= 1) ss += __shfl_xor(ss, m);
        if (lane == 0) pninv[row] = 1.f / fmaxf(sqrtf(ss), 1e-12f);
    } else if (b < 3506) {
        // B-frag for 16x16x32: lane holds B[k=(lane>>4)*8+j][n=lane&15], j=0..7
        int idx = (b - 3266) * 256 + threadIdx.x;        // 61440 threads
        int j = idx & 7, lane = (idx >> 3) & 63;
        int t = idx >> 9;
        int lane16 = lane & 15, quad = lane >> 4;
        if (t < 24) {                 // B1: Bmat[k][n] = proxy[n][k] (pninv applied later)
            int kt = t >> 2, nt = t & 3;
            int k = kt * 32 + quad * 8 + j, n = nt * 16 + lane16;
            B1[idx] = f2bf(proxy[(size_t)n * FEATD + k]);
        } else if (t < 48) {          // B2: pa@proxy, Bmat[k][n] = proxy[k][n]
            int tt = t - 24, kt = tt / 12, nt = tt % 12;
            int k = kt * 32 + quad * 8 + j, n = nt * 16 + lane16;
            B2[idx - 12288] = f2bf(proxy[(size_t)k * FEATD + n]);
        } else {                      // B3: o@gate_w^T, Bmat[k][n] = gate_w[n][k]
            int tt = t - 48, kt = tt / 12, nt = tt % 12;
            int k = kt * 32 + quad * 8 + j, n = nt * 16 + lane16;
            B3[idx - 24576] = f2bf(gate_w[(size_t)n * FEATD + k]);
        }
    } else if (b < 4678) {
        // pack edges: pe = s | (r<<16)   (s < 65536, r < 512)
        int t = (b - 3506) * 256 + threadIdx.x;          // need 300000
        if (t < NEDGE / 4) {
            int4 s4 = *reinterpret_cast<const int4*>(src + t * 4);
            int4 r4 = *reinterpret_cast<const int4*>(rel + t * 4);
            uint4 o;
            o.x = (unsigned)s4.x | ((unsigned)r4.x << 16);
            o.y = (unsigned)s4.y | ((unsigned)r4.y << 16);
            o.z = (unsigned)s4.z | ((unsigned)r4.z << 16);
            o.w = (unsigned)s4.w | ((unsigned)r4.w << 16);
            *reinterpret_cast<uint4*>(pedge + t * 4) = o;
        }
    } else {
        // B4[k][n] = sum_j proxy[k][j] * gate_w[n][j]  (k<64, n<192), frag order
        int t = (b - 4678) * 256 + threadIdx.x;          // 12288 threads
        int j = t & 7, lane = (t >> 3) & 63, tl = t >> 9;  // tl in [0,24)
        int lane16 = lane & 15, quad = lane >> 4;
        int kt = tl / 12, nt = tl % 12;
        int k = kt * 32 + quad * 8 + j, n = nt * 16 + lane16;
        const float4* pr = reinterpret_cast<const float4*>(proxy + (size_t)k * FEATD);
        const float4* gr = reinterpret_cast<const float4*>(gate_w + (size_t)n * FEATD);
        float acc = 0.f;
#pragma unroll 8
        for (int q = 0; q < 48; q++) {
            float4 a = pr[q], g4 = gr[q];
            acc += a.x * g4.x + a.y * g4.y + a.z * g4.z + a.w * g4.w;
        }
        B4[t] = f2bf(acc);
    }
}

// ---- Layer: per-node attention aggregation (R7-proven, bf16 feats) ----------
__global__ __launch_bounds__(256) void k_layer(const unsigned int* __restrict__ pedge,
                                               const float* __restrict__ reln,
                                               const float* __restrict__ expdot_l,
                                               const unsigned short* __restrict__ fin,
                                               unsigned short* __restrict__ fout) {
    int b = blockIdx.x;
    int lb = (b & 7) * LCHUNK + (b >> 3);
    int lane8 = threadIdx.x & 7;
    int node = lb * 32 + (threadIdx.x >> 3);
    if (node >= N_NODES) return;
    int ebase = node * DEG;
    unsigned pk[DEG];
#pragma unroll
    for (int k = 0; k < DEG; k++) pk[k] = pedge[ebase + k];
    float a0 = 0.f, a1 = 0.f, a2 = 0.f, a3 = 0.f;
    float a4 = 0.f, a5 = 0.f, a6 = 0.f, a7 = 0.f, den = 0.f;
#pragma unroll 4
    for (int k = 0; k < DEG; k++) {
        unsigned p = pk[k];
        int s = p & 0xFFFF;
        int r = p >> 16;
        float ex = expdot_l[r];
        const float* tp = reln + (size_t)r * 64 + lane8 * 8;
        float4 t0 = *reinterpret_cast<const float4*>(tp);
        float4 t1v = *reinterpret_cast<const float4*>(tp + 4);
        uint4 u = *reinterpret_cast<const uint4*>(fin + (size_t)s * 64 + lane8 * 8);
        float n0 = lo16(u.x), n1 = hi16(u.x), n2 = lo16(u.y), n3 = hi16(u.y);
        float n4 = lo16(u.z), n5 = hi16(u.z), n6 = lo16(u.w), n7 = hi16(u.w);
        float pd = t0.x * n0 + t0.y * n1 + t0.z * n2 + t0.w * n3
                 + t1v.x * n4 + t1v.y * n5 + t1v.z * n6 + t1v.w * n7;
        pd += __shfl_xor(pd, 1); pd += __shfl_xor(pd, 2); pd += __shfl_xor(pd, 4);
        float t1 = -2.f * pd * ex;          // acc += ex*(nv - 2*dot*tv)
        a0 = fmaf(ex, n0, fmaf(t1, t0.x, a0));
        a1 = fmaf(ex, n1, fmaf(t1, t0.y, a1));
        a2 = fmaf(ex, n2, fmaf(t1, t0.z, a2));
        a3 = fmaf(ex, n3, fmaf(t1, t0.w, a3));
        a4 = fmaf(ex, n4, fmaf(t1, t1v.x, a4));
        a5 = fmaf(ex, n5, fmaf(t1, t1v.y, a5));
        a6 = fmaf(ex, n6, fmaf(t1, t1v.z, a6));
        a7 = fmaf(ex, n7, fmaf(t1, t1v.w, a7));
        den += ex;
    }
    float id = 1.f / den;
    uint4 w;
    w.x = (unsigned)f2bf(fast_tanh(a0 * id)) | ((unsigned)f2bf(fast_tanh(a1 * id)) << 16);
    w.y = (unsigned)f2bf(fast_tanh(a2 * id)) | ((unsigned)f2bf(fast_tanh(a3 * id)) << 16);
    w.z = (unsigned)f2bf(fast_tanh(a4 * id)) | ((unsigned)f2bf(fast_tanh(a5 * id)) << 16);
    w.w = (unsigned)f2bf(fast_tanh(a6 * id)) | ((unsigned)f2bf(fast_tanh(a7 * id)) << 16);
    *reinterpret_cast<uint4*>(fout + (size_t)node * 64 + lane8 * 8) = w;
}

// ---- GATE (flattened + split-wave + identity-MFMA) --------------------------
// z = o@G^T - pa@(P@G^T) + b;  out = o - (1-g)*(pa@P).
// 2 waves per 16-row tile: each redundantly computes phase A (cheap), then
// owns 6 of the 12 nt output tiles -> 1563 blocks (~6/CU), halved per-wave
// critical path. o in C-layout obtained via MFMA with an in-register identity
// B-fragment (exact, zero memory traffic) instead of 48 scalar loads.
__global__ __launch_bounds__(256) void k_gate(const unsigned short* __restrict__ fin0,
                                              const unsigned short* __restrict__ fin1,
                                              const unsigned short* __restrict__ fin2,
                                              const unsigned short* __restrict__ B1,
                                              const unsigned short* __restrict__ B2,
                                              const unsigned short* __restrict__ B3,
                                              const unsigned short* __restrict__ B4,
                                              const float* __restrict__ pninv,
                                              const float* __restrict__ gate_b,
                                              float* __restrict__ dout) {
    __shared__ unsigned short lds[4][16 * PASTR];
    int wv = threadIdx.x >> 6, lane = threadIdx.x & 63;
    int g = blockIdx.x * 4 + wv;
    int tile = g >> 1;
    if (tile > NTILES - 1) tile = NTILES - 1;   // dup work, identical writes
    int half = g & 1;
    int row0 = tile * 16, lane16 = lane & 15, quad = lane >> 4;
    unsigned short* L = lds[wv];
    const unsigned short* fsel[3] = {fin0, fin1, fin2};

    // ---- Phase A: af frags + row norm + logits + softmax -> pa (normalized)
    bf16x8 af[6];
    float ss = 0.f;
#pragma unroll
    for (int kt = 0; kt < 6; kt++) {
        const unsigned short* f = fsel[kt >> 1];
        bf16x8 a = *reinterpret_cast<const bf16x8*>(f + (size_t)(row0 + lane16) * 64 + (kt & 1) * 32 + quad * 8);
        af[kt] = a;
#pragma unroll
        for (int i = 0; i < 8; i++) {
            float v = bf2f((unsigned short)a[i]);
            ss = fmaf(v, v, ss);
        }
    }
    ss += __shfl_xor(ss, 16); ss += __shfl_xor(ss, 32);   // full row sumsq at lane&15
    float inv = 1.f / fmaxf(sqrtf(ss), 1e-12f);
    float pni[4];
#pragma unroll
    for (int nt = 0; nt < 4; nt++) pni[nt] = pninv[nt * 16 + lane16];
    f32x4 acc4[4];
#pragma unroll
    for (int nt = 0; nt < 4; nt++) acc4[nt] = (f32x4){0.f, 0.f, 0.f, 0.f};
#pragma unroll
    for (int kt = 0; kt < 6; kt++) {
#pragma unroll
        for (int nt = 0; nt < 4; nt++) {
            bf16x8 bfr = *reinterpret_cast<const bf16x8*>(B1 + ((size_t)(kt * 4 + nt) * 64 + lane) * 8);
            acc4[nt] = __builtin_amdgcn_mfma_f32_16x16x32_bf16(af[kt], bfr, acc4[nt], 0, 0, 0);
        }
    }
    // softmax without max-sub: logits are cosine sims in [-1,1]
#pragma unroll
    for (int r = 0; r < 4; r++) {
        int rowloc = quad * 4 + r;
        float invr = __shfl(inv, rowloc);
        float e0 = __expf(acc4[0][r] * invr * pni[0]);
        float e1 = __expf(acc4[1][r] * invr * pni[1]);
        float e2 = __expf(acc4[2][r] * invr * pni[2]);
        float e3 = __expf(acc4[3][r] * invr * pni[3]);
        float s = e0 + e1 + e2 + e3;
        s += __shfl_xor(s, 1); s += __shfl_xor(s, 2);
        s += __shfl_xor(s, 4); s += __shfl_xor(s, 8);
        float rs = 1.f / s;
        L[rowloc * PASTR + lane16]      = f2bf(e0 * rs);
        L[rowloc * PASTR + 16 + lane16] = f2bf(e1 * rs);
        L[rowloc * PASTR + 32 + lane16] = f2bf(e2 * rs);
        L[rowloc * PASTR + 48 + lane16] = f2bf(e3 * rs);
    }
    __threadfence_block();   // drain pa writes (wave-private LDS; no s_barrier)

    // pa A-frags: the ONLY dependent loads after phase A
    bf16x8 paf0 = *reinterpret_cast<const bf16x8*>(L + lane16 * PASTR + quad * 8);
    bf16x8 paf1 = *reinterpret_cast<const bf16x8*>(L + lane16 * PASTR + 32 + quad * 8);

    // identity B-fragments (in-register): I0[k][n]=d(k,n), I1[k][n]=d(k-16,n)
    bf16x8 i0, i1;
#pragma unroll
    for (int j = 0; j < 8; j++) {
        int k = quad * 8 + j;
        i0[j] = (short)((k == lane16)      ? 0x3F80 : 0);
        i1[j] = (short)((k == lane16 + 16) ? 0x3F80 : 0);
    }

    // ---- this wave owns nt in [half*6, half*6+6), processed in 2 chunks of 3
#pragma unroll
    for (int c = 0; c < 2; c++) {
        int nt0 = half * 6 + c * 3;
        f32x4 s3[3], s4[3], s2[3], oc[3];
#pragma unroll
        for (int n = 0; n < 3; n++) {
            s3[n] = (f32x4){0.f, 0.f, 0.f, 0.f};
            s4[n] = (f32x4){0.f, 0.f, 0.f, 0.f};
            s2[n] = (f32x4){0.f, 0.f, 0.f, 0.f};
            oc[n] = (f32x4){0.f, 0.f, 0.f, 0.f};
        }
#pragma unroll
        for (int kt = 0; kt < 6; kt++) {
#pragma unroll
            for (int n = 0; n < 3; n++) {
                bf16x8 bfr = *reinterpret_cast<const bf16x8*>(B3 + ((size_t)(kt * 12 + nt0 + n) * 64 + lane) * 8);
                s3[n] = __builtin_amdgcn_mfma_f32_16x16x32_bf16(af[kt], bfr, s3[n], 0, 0, 0);
            }
        }
#pragma unroll
        for (int n = 0; n < 3; n++) {
            int nt = nt0 + n;
            bf16x8 b40 = *reinterpret_cast<const bf16x8*>(B4 + ((size_t)nt * 64 + lane) * 8);
            bf16x8 b41 = *reinterpret_cast<const bf16x8*>(B4 + ((size_t)(12 + nt) * 64 + lane) * 8);
            s4[n] = __builtin_amdgcn_mfma_f32_16x16x32_bf16(paf0, b40, s4[n], 0, 0, 0);
            s4[n] = __builtin_amdgcn_mfma_f32_16x16x32_bf16(paf1, b41, s4[n], 0, 0, 0);
            bf16x8 b20 = *reinterpret_cast<const bf16x8*>(B2 + ((size_t)nt * 64 + lane) * 8);
            bf16x8 b21 = *reinterpret_cast<const bf16x8*>(B2 + ((size_t)(12 + nt) * 64 + lane) * 8);
            s2[n] = __builtin_amdgcn_mfma_f32_16x16x32_bf16(paf0, b20, s2[n], 0, 0, 0);
            s2[n] = __builtin_amdgcn_mfma_f32_16x16x32_bf16(paf1, b21, s2[n], 0, 0, 0);
            // o tile in C-layout via identity MFMA (exact bf16 -> fp32)
            oc[n] = __builtin_amdgcn_mfma_f32_16x16x32_bf16(af[nt >> 1], (nt & 1) ? i1 : i0, oc[n], 0, 0, 0);
        }
#pragma unroll
        for (int n = 0; n < 3; n++) {
            int nt = nt0 + n;
            float bias = gate_b[nt * 16 + lane16];
#pragma unroll
            for (int r = 0; r < 4; r++) {
                int rowloc = quad * 4 + r;
                float z = s3[n][r] - s4[n][r] + bias;
                float gg = 1.f / (1.f + __expf(-z));
                dout[(size_t)(row0 + rowloc) * FEATD + nt * 16 + lane16] =
                    oc[n][r] - (1.f - gg) * s2[n][r];
            }
        }
    }
}

extern "C" void kernel_launch(void* const* d_in, const int* in_sizes, int n_in,
                              void* d_out, int out_size, void* d_ws, size_t ws_size,
                              hipStream_t stream) {
    (void)in_sizes; (void)n_in; (void)out_size; (void)ws_size;
    const float* features = (const float*)d_in[0];
    const float* rel_emb  = (const float*)d_in[1];
    const float* proxy    = (const float*)d_in[2];
    const float* gate_w   = (const float*)d_in[3];
    const float* gate_b   = (const float*)d_in[4];
    const float* attn_k   = (const float*)d_in[5];
    const int*   adj      = (const int*)d_in[6];
    const int*   r_index  = (const int*)d_in[7];
    // d_in[8] (r_val) unused: positive scale cancels under l2norm; r_index[0]==arange(E).

    unsigned short* fin0 = (unsigned short*)d_ws;           // N*64 bf16
    unsigned short* fin1 = fin0 + (size_t)N_NODES * 64;     // N*64 bf16
    unsigned short* fin2 = fin1 + (size_t)N_NODES * 64;     // N*64 bf16
    float* reln    = (float*)(fin2 + (size_t)N_NODES * 64); // 500*64 fp32
    float* expdot  = reln + RSZ * 64;                       // 2*500
    float* pninv   = expdot + 2 * RSZ;                      // 64
    unsigned short* B1 = (unsigned short*)(pninv + 64);     // 12288
    unsigned short* B2 = B1 + 12288;                        // 12288
    unsigned short* B3 = B2 + 12288;                        // 36864
    unsigned short* B4 = B3 + 36864;                        // 12288
    unsigned int* pedge = (unsigned int*)(B4 + 12288);      // NEDGE u32

    const int* src = adj + NEDGE;       // adj[1]
    const int* rel = r_index + NEDGE;   // r_index[1]

    k_prep  <<<dim3(4726), dim3(256), 0, stream>>>(features, rel_emb, attn_k, proxy, gate_w,
                                                   src, rel, fin0, reln, expdot,
                                                   pninv, B1, B2, B3, B4, pedge);
    k_layer <<<dim3(LGRID), dim3(256), 0, stream>>>(pedge, reln, expdot,       fin0, fin1);
    k_layer <<<dim3(LGRID), dim3(256), 0, stream>>>(pedge, reln, expdot + RSZ, fin1, fin2);
    k_gate  <<<dim3(1563), dim3(256), 0, stream>>>(fin0, fin1, fin2, B1, B2, B3, B4, pninv,
                                                   gate_b, (float*)d_out);
}

// Round 10
// 199.621 us; speedup vs baseline: 1.1762x; 1.1762x over previous
//
#include <hip/hip_runtime.h>
#include <hip/hip_bf16.h>
#include <cstdint>
#include <cstddef>

#define N_NODES 50000
#define DEG     24
#define NEDGE   (N_NODES*DEG)
#define RSZ     500
#define NDIM    64
#define FEATD   192
#define NTILES  (N_NODES/16)     // 3125

// LDS row stride (shorts) for the 16x64 pa transpose buffer in k_gate.
#define PASTR   72

// k_layer grid: 32 nodes/block (8 lanes x 8 dims per node), 1563 logical blocks,
// padded to 1568 = 8*196 for the XCD swizzle.
#define LGRID   1568
#define LCHUNK  196

typedef short bf16x8 __attribute__((ext_vector_type(8)));
typedef float f32x4  __attribute__((ext_vector_type(4)));

__device__ __forceinline__ unsigned short f2bf(float f) {
    unsigned u = __builtin_bit_cast(unsigned, f);
    unsigned r = (u + 0x7fffu + ((u >> 16) & 1u)) >> 16;   // RNE
    return (unsigned short)r;
}
__device__ __forceinline__ float bf2f(unsigned short s) {
    unsigned u = ((unsigned)s) << 16;
    return __builtin_bit_cast(float, u);
}
__device__ __forceinline__ float lo16(unsigned u) {
    return __builtin_bit_cast(float, u << 16);
}
__device__ __forceinline__ float hi16(unsigned u) {
    return __builtin_bit_cast(float, u & 0xFFFF0000u);
}
__device__ __forceinline__ float fast_tanh(float x) {
    float e = __expf(2.f * x);
    return 1.f - 2.f / (e + 1.f);
}

// ---- PREP (fused): tanh(features)->fin0 (bf16) | l2norm(rel)+exp(attdot) |
//      1/||proxy_n|| | pack B1/B2/B3 | pack edges | B4 = proxy @ gate_w^T.
__global__ __launch_bounds__(256) void k_prep(const float* __restrict__ features,
                                              const float* __restrict__ rel_emb,
                                              const float* __restrict__ attn_k,
                                              const float* __restrict__ proxy,
                                              const float* __restrict__ gate_w,
                                              const int* __restrict__ src,
                                              const int* __restrict__ rel,
                                              unsigned short* __restrict__ fin0,
                                              float* __restrict__ reln,
                                              float* __restrict__ expdot,
                                              float* __restrict__ pninv,
                                              unsigned short* __restrict__ B1,
                                              unsigned short* __restrict__ B2,
                                              unsigned short* __restrict__ B3,
                                              unsigned short* __restrict__ B4,
                                              unsigned int* __restrict__ pedge) {
    int b = blockIdx.x;
    if (b < 3125) {
        int t = b * 256 + threadIdx.x;             // 800000 threads, 4 elems each
        int idx4 = t * 4;
        float4 f = *reinterpret_cast<const float4*>(features + idx4);
        uint2 w;
        w.x = (unsigned)f2bf(fast_tanh(f.x)) | ((unsigned)f2bf(fast_tanh(f.y)) << 16);
        w.y = (unsigned)f2bf(fast_tanh(f.z)) | ((unsigned)f2bf(fast_tanh(f.w)) << 16);
        *reinterpret_cast<uint2*>(fin0 + idx4) = w;
    } else if (b < 3250) {
        int lane = threadIdx.x & 63;
        int row = (b - 3125) * 4 + (threadIdx.x >> 6);   // 500 rows
        float v = rel_emb[row * 64 + lane];
        float ss = v * v;
        for (int m = 1; m < 64; m <<= 1) ss += __shfl_xor(ss, m);
        float inv = 1.f / fmaxf(sqrtf(ss), 1e-12f);
        float rn = v * inv;
        reln[row * 64 + lane] = rn;
        float d0 = rn * attn_k[lane];
        float d1 = rn * attn_k[64 + lane];
        for (int m = 1; m < 64; m <<= 1) { d0 += __shfl_xor(d0, m); d1 += __shfl_xor(d1, m); }
        if (lane == 0) { expdot[row] = __expf(d0); expdot[RSZ + row] = __expf(d1); }
    } else if (b < 3266) {
        int lane = threadIdx.x & 63;
        int row = (b - 3250) * 4 + (threadIdx.x >> 6);   // 64 rows
        const float* p = proxy + (size_t)row * FEATD;
        float a = p[lane], bb = p[64 + lane], c = p[128 + lane];
        float ss = a * a + bb * bb + c * c;
        for (int m = 1; m < 64; m <<= 1) ss += __shfl_xor(ss, m);
        if (lane == 0) pninv[row] = 1.f / fmaxf(sqrtf(ss), 1e-12f);
    } else if (b < 3506) {
        // B-frag for 16x16x32: lane holds B[k=(lane>>4)*8+j][n=lane&15], j=0..7
        int idx = (b - 3266) * 256 + threadIdx.x;        // 61440 threads
        int j = idx & 7, lane = (idx >> 3) & 63;
        int t = idx >> 9;
        int lane16 = lane & 15, quad = lane >> 4;
        if (t < 24) {                 // B1: Bmat[k][n] = proxy[n][k] (pninv applied later)
            int kt = t >> 2, nt = t & 3;
            int k = kt * 32 + quad * 8 + j, n = nt * 16 + lane16;
            B1[idx] = f2bf(proxy[(size_t)n * FEATD + k]);
        } else if (t < 48) {          // B2: pa@proxy, Bmat[k][n] = proxy[k][n]
            int tt = t - 24, kt = tt / 12, nt = tt % 12;
            int k = kt * 32 + quad * 8 + j, n = nt * 16 + lane16;
            B2[idx - 12288] = f2bf(proxy[(size_t)k * FEATD + n]);
        } else {                      // B3: o@gate_w^T, Bmat[k][n] = gate_w[n][k]
            int tt = t - 48, kt = tt / 12, nt = tt % 12;
            int k = kt * 32 + quad * 8 + j, n = nt * 16 + lane16;
            B3[idx - 24576] = f2bf(gate_w[(size_t)n * FEATD + k]);
        }
    } else if (b < 4678) {
        // pack edges: pe = s | (r<<16)
        int t = (b - 3506) * 256 + threadIdx.x;
        if (t < NEDGE / 4) {
            int4 s4 = *reinterpret_cast<const int4*>(src + t * 4);
            int4 r4 = *reinterpret_cast<const int4*>(rel + t * 4);
            uint4 o;
            o.x = (unsigned)s4.x | ((unsigned)r4.x << 16);
            o.y = (unsigned)s4.y | ((unsigned)r4.y << 16);
            o.z = (unsigned)s4.z | ((unsigned)r4.z << 16);
            o.w = (unsigned)s4.w | ((unsigned)r4.w << 16);
            *reinterpret_cast<uint4*>(pedge + t * 4) = o;
        }
    } else {
        // B4[k][n] = sum_j proxy[k][j] * gate_w[n][j]  (k<64, n<192), frag order
        int t = (b - 4678) * 256 + threadIdx.x;          // 12288 threads
        int j = t & 7, lane = (t >> 3) & 63, tl = t >> 9;
        int lane16 = lane & 15, quad = lane >> 4;
        int kt = tl / 12, nt = tl % 12;
        int k = kt * 32 + quad * 8 + j, n = nt * 16 + lane16;
        const float4* pr = reinterpret_cast<const float4*>(proxy + (size_t)k * FEATD);
        const float4* gr = reinterpret_cast<const float4*>(gate_w + (size_t)n * FEATD);
        float acc = 0.f;
#pragma unroll 8
        for (int q = 0; q < 48; q++) {
            float4 a = pr[q], g4 = gr[q];
            acc += a.x * g4.x + a.y * g4.y + a.z * g4.z + a.w * g4.w;
        }
        B4[t] = f2bf(acc);
    }
}

// ---- Layer: per-node attention aggregation (R7-proven, bf16 feats) ----------
__global__ __launch_bounds__(256) void k_layer(const unsigned int* __restrict__ pedge,
                                               const float* __restrict__ reln,
                                               const float* __restrict__ expdot_l,
                                               const unsigned short* __restrict__ fin,
                                               unsigned short* __restrict__ fout) {
    int b = blockIdx.x;
    int lb = (b & 7) * LCHUNK + (b >> 3);
    int lane8 = threadIdx.x & 7;
    int node = lb * 32 + (threadIdx.x >> 3);
    if (node >= N_NODES) return;
    int ebase = node * DEG;
    unsigned pk[DEG];
#pragma unroll
    for (int k = 0; k < DEG; k++) pk[k] = pedge[ebase + k];
    float a0 = 0.f, a1 = 0.f, a2 = 0.f, a3 = 0.f;
    float a4 = 0.f, a5 = 0.f, a6 = 0.f, a7 = 0.f, den = 0.f;
#pragma unroll 4
    for (int k = 0; k < DEG; k++) {
        unsigned p = pk[k];
        int s = p & 0xFFFF;
        int r = p >> 16;
        float ex = expdot_l[r];
        const float* tp = reln + (size_t)r * 64 + lane8 * 8;
        float4 t0 = *reinterpret_cast<const float4*>(tp);
        float4 t1v = *reinterpret_cast<const float4*>(tp + 4);
        uint4 u = *reinterpret_cast<const uint4*>(fin + (size_t)s * 64 + lane8 * 8);
        float n0 = lo16(u.x), n1 = hi16(u.x), n2 = lo16(u.y), n3 = hi16(u.y);
        float n4 = lo16(u.z), n5 = hi16(u.z), n6 = lo16(u.w), n7 = hi16(u.w);
        float pd = t0.x * n0 + t0.y * n1 + t0.z * n2 + t0.w * n3
                 + t1v.x * n4 + t1v.y * n5 + t1v.z * n6 + t1v.w * n7;
        pd += __shfl_xor(pd, 1); pd += __shfl_xor(pd, 2); pd += __shfl_xor(pd, 4);
        float t1 = -2.f * pd * ex;          // acc += ex*(nv - 2*dot*tv)
        a0 = fmaf(ex, n0, fmaf(t1, t0.x, a0));
        a1 = fmaf(ex, n1, fmaf(t1, t0.y, a1));
        a2 = fmaf(ex, n2, fmaf(t1, t0.z, a2));
        a3 = fmaf(ex, n3, fmaf(t1, t0.w, a3));
        a4 = fmaf(ex, n4, fmaf(t1, t1v.x, a4));
        a5 = fmaf(ex, n5, fmaf(t1, t1v.y, a5));
        a6 = fmaf(ex, n6, fmaf(t1, t1v.z, a6));
        a7 = fmaf(ex, n7, fmaf(t1, t1v.w, a7));
        den += ex;
    }
    float id = 1.f / den;
    uint4 w;
    w.x = (unsigned)f2bf(fast_tanh(a0 * id)) | ((unsigned)f2bf(fast_tanh(a1 * id)) << 16);
    w.y = (unsigned)f2bf(fast_tanh(a2 * id)) | ((unsigned)f2bf(fast_tanh(a3 * id)) << 16);
    w.z = (unsigned)f2bf(fast_tanh(a4 * id)) | ((unsigned)f2bf(fast_tanh(a5 * id)) << 16);
    w.w = (unsigned)f2bf(fast_tanh(a6 * id)) | ((unsigned)f2bf(fast_tanh(a7 * id)) << 16);
    *reinterpret_cast<uint4*>(fout + (size_t)node * 64 + lane8 * 8) = w;
}

// ---- gate half-tile worker: H is COMPILE-TIME so all af/B indices are
// constants (R9's runtime `half` caused dynamic register indexing -> VALU x3).
template<int H>
__device__ __forceinline__ void gate_half(const bf16x8 (&af)[6], bf16x8 paf0, bf16x8 paf1,
                                          const unsigned short* __restrict__ B2,
                                          const unsigned short* __restrict__ B3,
                                          const unsigned short* __restrict__ B4,
                                          const float* __restrict__ gate_b,
                                          float* __restrict__ dout,
                                          int row0, int lane, int lane16, int quad,
                                          bf16x8 i0, bf16x8 i1) {
#pragma unroll
    for (int c = 0; c < 2; c++) {
        const int nt0 = H * 6 + c * 3;
        f32x4 s3[3], s4[3], s2[3], oc[3];
#pragma unroll
        for (int n = 0; n < 3; n++) {
            s3[n] = (f32x4){0.f, 0.f, 0.f, 0.f};
            s4[n] = (f32x4){0.f, 0.f, 0.f, 0.f};
            s2[n] = (f32x4){0.f, 0.f, 0.f, 0.f};
            oc[n] = (f32x4){0.f, 0.f, 0.f, 0.f};
        }
#pragma unroll
        for (int kt = 0; kt < 6; kt++) {
#pragma unroll
            for (int n = 0; n < 3; n++) {
                bf16x8 bfr = *reinterpret_cast<const bf16x8*>(B3 + ((size_t)(kt * 12 + nt0 + n) * 64 + lane) * 8);
                s3[n] = __builtin_amdgcn_mfma_f32_16x16x32_bf16(af[kt], bfr, s3[n], 0, 0, 0);
            }
        }
#pragma unroll
        for (int n = 0; n < 3; n++) {
            const int nt = nt0 + n;
            bf16x8 b40 = *reinterpret_cast<const bf16x8*>(B4 + ((size_t)nt * 64 + lane) * 8);
            bf16x8 b41 = *reinterpret_cast<const bf16x8*>(B4 + ((size_t)(12 + nt) * 64 + lane) * 8);
            s4[n] = __builtin_amdgcn_mfma_f32_16x16x32_bf16(paf0, b40, s4[n], 0, 0, 0);
            s4[n] = __builtin_amdgcn_mfma_f32_16x16x32_bf16(paf1, b41, s4[n], 0, 0, 0);
            bf16x8 b20 = *reinterpret_cast<const bf16x8*>(B2 + ((size_t)nt * 64 + lane) * 8);
            bf16x8 b21 = *reinterpret_cast<const bf16x8*>(B2 + ((size_t)(12 + nt) * 64 + lane) * 8);
            s2[n] = __builtin_amdgcn_mfma_f32_16x16x32_bf16(paf0, b20, s2[n], 0, 0, 0);
            s2[n] = __builtin_amdgcn_mfma_f32_16x16x32_bf16(paf1, b21, s2[n], 0, 0, 0);
            // o tile in C-layout via identity MFMA: af index is CONSTANT here
            oc[n] = __builtin_amdgcn_mfma_f32_16x16x32_bf16(af[nt >> 1], (nt & 1) ? i1 : i0, oc[n], 0, 0, 0);
        }
#pragma unroll
        for (int n = 0; n < 3; n++) {
            const int nt = nt0 + n;
            float bias = gate_b[nt * 16 + lane16];
#pragma unroll
            for (int r = 0; r < 4; r++) {
                int rowloc = quad * 4 + r;
                float z = s3[n][r] - s4[n][r] + bias;
                float gg = 1.f / (1.f + __expf(-z));
                dout[(size_t)(row0 + rowloc) * FEATD + nt * 16 + lane16] =
                    oc[n][r] - (1.f - gg) * s2[n][r];
            }
        }
    }
}

// ---- GATE (flattened + split-wave, compile-time half) -----------------------
// z = o@G^T - pa@(P@G^T) + b;  out = o - (1-g)*(pa@P).
// 2 waves per 16-row tile (each redoes cheap phase A, owns 6 nt tiles) ->
// 6252 waves (~24/CU available) for cross-wave latency hiding.
__global__ __launch_bounds__(256) void k_gate(const unsigned short* __restrict__ fin0,
                                              const unsigned short* __restrict__ fin1,
                                              const unsigned short* __restrict__ fin2,
                                              const unsigned short* __restrict__ B1,
                                              const unsigned short* __restrict__ B2,
                                              const unsigned short* __restrict__ B3,
                                              const unsigned short* __restrict__ B4,
                                              const float* __restrict__ pninv,
                                              const float* __restrict__ gate_b,
                                              float* __restrict__ dout) {
    __shared__ unsigned short lds[4][16 * PASTR];
    int wv = threadIdx.x >> 6, lane = threadIdx.x & 63;
    int g = blockIdx.x * 4 + wv;
    int tile = g >> 1;
    if (tile > NTILES - 1) tile = NTILES - 1;   // dup work, identical writes
    int half = g & 1;
    int row0 = tile * 16, lane16 = lane & 15, quad = lane >> 4;
    unsigned short* L = lds[wv];
    const unsigned short* fsel[3] = {fin0, fin1, fin2};

    // ---- Phase A: af frags + row norm + logits + softmax -> pa (normalized)
    bf16x8 af[6];
    float ss = 0.f;
#pragma unroll
    for (int kt = 0; kt < 6; kt++) {
        const unsigned short* f = fsel[kt >> 1];
        bf16x8 a = *reinterpret_cast<const bf16x8*>(f + (size_t)(row0 + lane16) * 64 + (kt & 1) * 32 + quad * 8);
        af[kt] = a;
#pragma unroll
        for (int i = 0; i < 8; i++) {
            float v = bf2f((unsigned short)a[i]);
            ss = fmaf(v, v, ss);
        }
    }
    ss += __shfl_xor(ss, 16); ss += __shfl_xor(ss, 32);
    float inv = 1.f / fmaxf(sqrtf(ss), 1e-12f);
    float pni[4];
#pragma unroll
    for (int nt = 0; nt < 4; nt++) pni[nt] = pninv[nt * 16 + lane16];
    f32x4 acc4[4];
#pragma unroll
    for (int nt = 0; nt < 4; nt++) acc4[nt] = (f32x4){0.f, 0.f, 0.f, 0.f};
#pragma unroll
    for (int kt = 0; kt < 6; kt++) {
#pragma unroll
        for (int nt = 0; nt < 4; nt++) {
            bf16x8 bfr = *reinterpret_cast<const bf16x8*>(B1 + ((size_t)(kt * 4 + nt) * 64 + lane) * 8);
            acc4[nt] = __builtin_amdgcn_mfma_f32_16x16x32_bf16(af[kt], bfr, acc4[nt], 0, 0, 0);
        }
    }
    // softmax without max-sub: logits are cosine sims in [-1,1]
#pragma unroll
    for (int r = 0; r < 4; r++) {
        int rowloc = quad * 4 + r;
        float invr = __shfl(inv, rowloc);
        float e0 = __expf(acc4[0][r] * invr * pni[0]);
        float e1 = __expf(acc4[1][r] * invr * pni[1]);
        float e2 = __expf(acc4[2][r] * invr * pni[2]);
        float e3 = __expf(acc4[3][r] * invr * pni[3]);
        float s = e0 + e1 + e2 + e3;
        s += __shfl_xor(s, 1); s += __shfl_xor(s, 2);
        s += __shfl_xor(s, 4); s += __shfl_xor(s, 8);
        float rs = 1.f / s;
        L[rowloc * PASTR + lane16]      = f2bf(e0 * rs);
        L[rowloc * PASTR + 16 + lane16] = f2bf(e1 * rs);
        L[rowloc * PASTR + 32 + lane16] = f2bf(e2 * rs);
        L[rowloc * PASTR + 48 + lane16] = f2bf(e3 * rs);
    }
    __threadfence_block();   // drain pa writes (wave-private LDS; no s_barrier)

    bf16x8 paf0 = *reinterpret_cast<const bf16x8*>(L + lane16 * PASTR + quad * 8);
    bf16x8 paf1 = *reinterpret_cast<const bf16x8*>(L + lane16 * PASTR + 32 + quad * 8);

    // identity B-fragments: I0[k][n]=d(k,n), I1[k][n]=d(k-16,n)
    bf16x8 i0, i1;
#pragma unroll
    for (int j = 0; j < 8; j++) {
        int k = quad * 8 + j;
        i0[j] = (short)((k == lane16)      ? 0x3F80 : 0);
        i1[j] = (short)((k == lane16 + 16) ? 0x3F80 : 0);
    }

    if (half == 0)
        gate_half<0>(af, paf0, paf1, B2, B3, B4, gate_b, dout, row0, lane, lane16, quad, i0, i1);
    else
        gate_half<1>(af, paf0, paf1, B2, B3, B4, gate_b, dout, row0, lane, lane16, quad, i0, i1);
}

extern "C" void kernel_launch(void* const* d_in, const int* in_sizes, int n_in,
                              void* d_out, int out_size, void* d_ws, size_t ws_size,
                              hipStream_t stream) {
    (void)in_sizes; (void)n_in; (void)out_size; (void)ws_size;
    const float* features = (const float*)d_in[0];
    const float* rel_emb  = (const float*)d_in[1];
    const float* proxy    = (const float*)d_in[2];
    const float* gate_w   = (const float*)d_in[3];
    const float* gate_b   = (const float*)d_in[4];
    const float* attn_k   = (const float*)d_in[5];
    const int*   adj      = (const int*)d_in[6];
    const int*   r_index  = (const int*)d_in[7];
    // d_in[8] (r_val) unused: positive scale cancels under l2norm; r_index[0]==arange(E).

    unsigned short* fin0 = (unsigned short*)d_ws;           // N*64 bf16
    unsigned short* fin1 = fin0 + (size_t)N_NODES * 64;     // N*64 bf16
    unsigned short* fin2 = fin1 + (size_t)N_NODES * 64;     // N*64 bf16
    float* reln    = (float*)(fin2 + (size_t)N_NODES * 64); // 500*64 fp32
    float* expdot  = reln + RSZ * 64;                       // 2*500
    float* pninv   = expdot + 2 * RSZ;                      // 64
    unsigned short* B1 = (unsigned short*)(pninv + 64);     // 12288
    unsigned short* B2 = B1 + 12288;                        // 12288
    unsigned short* B3 = B2 + 12288;                        // 36864
    unsigned short* B4 = B3 + 36864;                        // 12288
    unsigned int* pedge = (unsigned int*)(B4 + 12288);      // NEDGE u32

    const int* src = adj + NEDGE;       // adj[1]
    const int* rel = r_index + NEDGE;   // r_index[1]

    k_prep  <<<dim3(4726), dim3(256), 0, stream>>>(features, rel_emb, attn_k, proxy, gate_w,
                                                   src, rel, fin0, reln, expdot,
                                                   pninv, B1, B2, B3, B4, pedge);
    k_layer <<<dim3(LGRID), dim3(256), 0, stream>>>(pedge, reln, expdot,       fin0, fin1);
    k_layer <<<dim3(LGRID), dim3(256), 0, stream>>>(pedge, reln, expdot + RSZ, fin1, fin2);
    k_gate  <<<dim3(1563), dim3(256), 0, stream>>>(fin0, fin1, fin2, B1, B2, B3, B4, pninv,
                                                   gate_b, (float*)d_out);
}

// Round 11
// 188.675 us; speedup vs baseline: 1.2445x; 1.0580x over previous
//
#include <hip/hip_runtime.h>
#include <hip/hip_bf16.h>
#include <cstdint>
#include <cstddef>

#define N_NODES 50000
#define DEG     24
#define NEDGE   (N_NODES*DEG)
#define RSZ     500
#define NDIM    64
#define FEATD   192
#define NTILES  (N_NODES/16)     // 3125

// LDS row stride (shorts) for the 16x200 per-wave transpose buffer in k_gate.
#define LSTR    200

// XCD-aligned chunking: all producers/consumers of fin*/pedge use block->XCD
// round-robin (b%8) with contiguous per-XCD data chunks of 6272 nodes.
#define LGRID   1568
#define LCHUNK  196     // k_layer: 196 blocks/XCD x 32 nodes = 6272 nodes
#define TGRID   3136
#define TCHUNK  392     // prep-tanh: 392 blocks/XCD x 16 nodes = 6272 nodes
#define EGRID   1176
#define ECHUNK  147     // packE: 147 blocks/XCD x 256 dwords(x4 edges) = 6272 nodes
#define GGRID   784
#define GCHUNK  98      // k_gate: 98 blocks/XCD x 4 tiles x 16 rows = 6272 nodes

typedef short bf16x8 __attribute__((ext_vector_type(8)));
typedef float f32x4  __attribute__((ext_vector_type(4)));

__device__ __forceinline__ unsigned short f2bf(float f) {
    unsigned u = __builtin_bit_cast(unsigned, f);
    unsigned r = (u + 0x7fffu + ((u >> 16) & 1u)) >> 16;   // RNE
    return (unsigned short)r;
}
__device__ __forceinline__ float bf2f(unsigned short s) {
    unsigned u = ((unsigned)s) << 16;
    return __builtin_bit_cast(float, u);
}
__device__ __forceinline__ float lo16(unsigned u) {
    return __builtin_bit_cast(float, u << 16);
}
__device__ __forceinline__ float hi16(unsigned u) {
    return __builtin_bit_cast(float, u & 0xFFFF0000u);
}
__device__ __forceinline__ float fast_tanh(float x) {
    float e = __expf(2.f * x);
    return 1.f - 2.f / (e + 1.f);
}

// ---- PREP (fused): tanh->fin0 (XCD-aligned) | rel | pninv | packB | packE.
// Block ranges: [0,3136) tanh, [3136,3261) rel, [3261,3277) pninv,
//               [3277,3517) packB, [3517,4693) packE.
__global__ __launch_bounds__(256) void k_prep(const float* __restrict__ features,
                                              const float* __restrict__ rel_emb,
                                              const float* __restrict__ attn_k,
                                              const float* __restrict__ proxy,
                                              const float* __restrict__ gate_w,
                                              const int* __restrict__ src,
                                              const int* __restrict__ rel,
                                              unsigned short* __restrict__ fin0,
                                              float* __restrict__ reln,
                                              float* __restrict__ expdot,
                                              float* __restrict__ pninv,
                                              unsigned short* __restrict__ B1,
                                              unsigned short* __restrict__ B2,
                                              unsigned short* __restrict__ B3,
                                              unsigned int* __restrict__ pedge) {
    int b = blockIdx.x;
    if (b < TGRID) {
        // tanh -> fin0, XCD-aligned: XCD x writes nodes [x*6272,(x+1)*6272)
        int lb = (b & 7) * TCHUNK + (b >> 3);      // 0..3135
        int idx4 = (lb * 256 + threadIdx.x) * 4;   // 16 nodes/block
        if (idx4 < N_NODES * 64) {
            float4 f = *reinterpret_cast<const float4*>(features + idx4);
            uint2 w;
            w.x = (unsigned)f2bf(fast_tanh(f.x)) | ((unsigned)f2bf(fast_tanh(f.y)) << 16);
            w.y = (unsigned)f2bf(fast_tanh(f.z)) | ((unsigned)f2bf(fast_tanh(f.w)) << 16);
            *reinterpret_cast<uint2*>(fin0 + idx4) = w;
        }
    } else if (b < 3261) {
        int lane = threadIdx.x & 63;
        int row = (b - TGRID) * 4 + (threadIdx.x >> 6);   // 500 rows
        float v = rel_emb[row * 64 + lane];
        float ss = v * v;
        for (int m = 1; m < 64; m <<= 1) ss += __shfl_xor(ss, m);
        float inv = 1.f / fmaxf(sqrtf(ss), 1e-12f);
        float rn = v * inv;
        reln[row * 64 + lane] = rn;
        float d0 = rn * attn_k[lane];
        float d1 = rn * attn_k[64 + lane];
        for (int m = 1; m < 64; m <<= 1) { d0 += __shfl_xor(d0, m); d1 += __shfl_xor(d1, m); }
        if (lane == 0) { expdot[row] = __expf(d0); expdot[RSZ + row] = __expf(d1); }
    } else if (b < 3277) {
        int lane = threadIdx.x & 63;
        int row = (b - 3261) * 4 + (threadIdx.x >> 6);   // 64 rows
        const float* p = proxy + (size_t)row * FEATD;
        float a = p[lane], bb = p[64 + lane], c = p[128 + lane];
        float ss = a * a + bb * bb + c * c;
        for (int m = 1; m < 64; m <<= 1) ss += __shfl_xor(ss, m);
        if (lane == 0) pninv[row] = 1.f / fmaxf(sqrtf(ss), 1e-12f);
    } else if (b < 3517) {
        // B-frag for 16x16x32: lane holds B[k=(lane>>4)*8+j][n=lane&15], j=0..7
        int idx = (b - 3277) * 256 + threadIdx.x;        // 61440 threads
        int j = idx & 7, lane = (idx >> 3) & 63;
        int t = idx >> 9;
        int lane16 = lane & 15, quad = lane >> 4;
        if (t < 24) {                 // B1: Bmat[k][n] = proxy[n][k] (pninv applied later)
            int kt = t >> 2, nt = t & 3;
            int k = kt * 32 + quad * 8 + j, n = nt * 16 + lane16;
            B1[idx] = f2bf(proxy[(size_t)n * FEATD + k]);
        } else if (t < 48) {          // B2: pa@proxy, Bmat[k][n] = proxy[k][n]
            int tt = t - 24, kt = tt / 12, nt = tt % 12;
            int k = kt * 32 + quad * 8 + j, n = nt * 16 + lane16;
            B2[idx - 12288] = f2bf(proxy[(size_t)k * FEATD + n]);
        } else {                      // B3: pf@gate_w^T, Bmat[k][n] = gate_w[n][k]
            int tt = t - 48, kt = tt / 12, nt = tt % 12;
            int k = kt * 32 + quad * 8 + j, n = nt * 16 + lane16;
            B3[idx - 24576] = f2bf(gate_w[(size_t)n * FEATD + k]);
        }
    } else {
        // pack edges (XCD-aligned): pe = s | (r<<16)
        int lb = ((b - 3517) & 7) * ECHUNK + ((b - 3517) >> 3);   // 0..1175
        int t = lb * 256 + threadIdx.x;
        if (t < NEDGE / 4) {
            int4 s4 = *reinterpret_cast<const int4*>(src + t * 4);
            int4 r4 = *reinterpret_cast<const int4*>(rel + t * 4);
            uint4 o;
            o.x = (unsigned)s4.x | ((unsigned)r4.x << 16);
            o.y = (unsigned)s4.y | ((unsigned)r4.y << 16);
            o.z = (unsigned)s4.z | ((unsigned)r4.z << 16);
            o.w = (unsigned)s4.w | ((unsigned)r4.w << 16);
            *reinterpret_cast<uint4*>(pedge + t * 4) = o;
        }
    }
}

// ---- Layer: per-node attention aggregation (R7-proven, bf16 feats) ----------
__global__ __launch_bounds__(256) void k_layer(const unsigned int* __restrict__ pedge,
                                               const float* __restrict__ reln,
                                               const float* __restrict__ expdot_l,
                                               const unsigned short* __restrict__ fin,
                                               unsigned short* __restrict__ fout) {
    int b = blockIdx.x;
    int lb = (b & 7) * LCHUNK + (b >> 3);
    int lane8 = threadIdx.x & 7;
    int node = lb * 32 + (threadIdx.x >> 3);
    if (node >= N_NODES) return;
    int ebase = node * DEG;
    unsigned pk[DEG];
#pragma unroll
    for (int k = 0; k < DEG; k++) pk[k] = pedge[ebase + k];
    float a0 = 0.f, a1 = 0.f, a2 = 0.f, a3 = 0.f;
    float a4 = 0.f, a5 = 0.f, a6 = 0.f, a7 = 0.f, den = 0.f;
#pragma unroll 4
    for (int k = 0; k < DEG; k++) {
        unsigned p = pk[k];
        int s = p & 0xFFFF;
        int r = p >> 16;
        float ex = expdot_l[r];
        const float* tp = reln + (size_t)r * 64 + lane8 * 8;
        float4 t0 = *reinterpret_cast<const float4*>(tp);
        float4 t1v = *reinterpret_cast<const float4*>(tp + 4);
        uint4 u = *reinterpret_cast<const uint4*>(fin + (size_t)s * 64 + lane8 * 8);
        float n0 = lo16(u.x), n1 = hi16(u.x), n2 = lo16(u.y), n3 = hi16(u.y);
        float n4 = lo16(u.z), n5 = hi16(u.z), n6 = lo16(u.w), n7 = hi16(u.w);
        float pd = t0.x * n0 + t0.y * n1 + t0.z * n2 + t0.w * n3
                 + t1v.x * n4 + t1v.y * n5 + t1v.z * n6 + t1v.w * n7;
        pd += __shfl_xor(pd, 1); pd += __shfl_xor(pd, 2); pd += __shfl_xor(pd, 4);
        float t1 = -2.f * pd * ex;          // acc += ex*(nv - 2*dot*tv)
        a0 = fmaf(ex, n0, fmaf(t1, t0.x, a0));
        a1 = fmaf(ex, n1, fmaf(t1, t0.y, a1));
        a2 = fmaf(ex, n2, fmaf(t1, t0.z, a2));
        a3 = fmaf(ex, n3, fmaf(t1, t0.w, a3));
        a4 = fmaf(ex, n4, fmaf(t1, t1v.x, a4));
        a5 = fmaf(ex, n5, fmaf(t1, t1v.y, a5));
        a6 = fmaf(ex, n6, fmaf(t1, t1v.z, a6));
        a7 = fmaf(ex, n7, fmaf(t1, t1v.w, a7));
        den += ex;
    }
    float id = 1.f / den;
    uint4 w;
    w.x = (unsigned)f2bf(fast_tanh(a0 * id)) | ((unsigned)f2bf(fast_tanh(a1 * id)) << 16);
    w.y = (unsigned)f2bf(fast_tanh(a2 * id)) | ((unsigned)f2bf(fast_tanh(a3 * id)) << 16);
    w.z = (unsigned)f2bf(fast_tanh(a4 * id)) | ((unsigned)f2bf(fast_tanh(a5 * id)) << 16);
    w.w = (unsigned)f2bf(fast_tanh(a6 * id)) | ((unsigned)f2bf(fast_tanh(a7 * id)) << 16);
    *reinterpret_cast<uint4*>(fout + (size_t)node * 64 + lane8 * 8) = w;
}

// ---- GATE (R7-proven body; XCD-aligned tile mapping) ------------------------
// Block b -> XCD b%8; XCD x gates tiles [x*392,(x+1)*392) = exactly the node
// rows its own k_layer/prep blocks produced (fin reads stay in local L2).
__global__ __launch_bounds__(256) void k_gate(const unsigned short* __restrict__ fin0,
                                              const unsigned short* __restrict__ fin1,
                                              const unsigned short* __restrict__ fin2,
                                              const unsigned short* __restrict__ B1,
                                              const unsigned short* __restrict__ B2,
                                              const unsigned short* __restrict__ B3,
                                              const float* __restrict__ pninv,
                                              const float* __restrict__ gate_b,
                                              float* __restrict__ dout) {
    __shared__ unsigned short lds[4][16 * LSTR];
    int wv = threadIdx.x >> 6, lane = threadIdx.x & 63;
    int lb = (blockIdx.x & 7) * GCHUNK + (blockIdx.x >> 3);   // 0..783
    int tile = lb * 4 + wv;
    if (tile > NTILES - 1) tile = NTILES - 1;  // dup work, identical writes
    int row0 = tile * 16, lane16 = lane & 15, quad = lane >> 4;
    unsigned short* L = lds[wv];
    const unsigned short* fsel[3] = {fin0, fin1, fin2};

    // o in C-layout (rows quad*4+r, col nt*16+lane16) — independent, issue early
    float oreg[12][4];
#pragma unroll
    for (int nt = 0; nt < 12; nt++) {
        const unsigned short* f = fsel[nt >> 2];
#pragma unroll
        for (int r = 0; r < 4; r++)
            oreg[nt][r] = bf2f(f[(size_t)(row0 + quad * 4 + r) * 64 + (nt & 3) * 16 + lane16]);
    }

    // af: direct 16B bf16 A-fragment loads; sumsq via cvt
    bf16x8 af[6];
    float ss = 0.f;
#pragma unroll
    for (int kt = 0; kt < 6; kt++) {
        const unsigned short* f = fsel[kt >> 1];
        bf16x8 a = *reinterpret_cast<const bf16x8*>(f + (size_t)(row0 + lane16) * 64 + (kt & 1) * 32 + quad * 8);
        af[kt] = a;
#pragma unroll
        for (int i = 0; i < 8; i++) {
            float v = bf2f((unsigned short)a[i]);
            ss = fmaf(v, v, ss);
        }
    }
    ss += __shfl_xor(ss, 16); ss += __shfl_xor(ss, 32);   // full row sumsq at lane&15
    float inv = 1.f / fmaxf(sqrtf(ss), 1e-12f);
    float pni[4];
#pragma unroll
    for (int nt = 0; nt < 4; nt++) pni[nt] = pninv[nt * 16 + lane16];
    f32x4 acc4[4];
#pragma unroll
    for (int nt = 0; nt < 4; nt++) acc4[nt] = (f32x4){0.f, 0.f, 0.f, 0.f};
#pragma unroll
    for (int kt = 0; kt < 6; kt++) {
#pragma unroll
        for (int nt = 0; nt < 4; nt++) {
            bf16x8 bfr = *reinterpret_cast<const bf16x8*>(B1 + ((size_t)(kt * 4 + nt) * 64 + lane) * 8);
            acc4[nt] = __builtin_amdgcn_mfma_f32_16x16x32_bf16(af[kt], bfr, acc4[nt], 0, 0, 0);
        }
    }
    // softmax without max-sub: logits are cosine sims in [-1,1]
#pragma unroll
    for (int r = 0; r < 4; r++) {
        int rowloc = quad * 4 + r;
        float invr = __shfl(inv, rowloc);
        float e0 = __expf(acc4[0][r] * invr * pni[0]);
        float e1 = __expf(acc4[1][r] * invr * pni[1]);
        float e2 = __expf(acc4[2][r] * invr * pni[2]);
        float e3 = __expf(acc4[3][r] * invr * pni[3]);
        float s = e0 + e1 + e2 + e3;
        s += __shfl_xor(s, 1); s += __shfl_xor(s, 2);
        s += __shfl_xor(s, 4); s += __shfl_xor(s, 8);
        float rs = 1.f / s;
        L[rowloc * LSTR + lane16]      = f2bf(e0 * rs);
        L[rowloc * LSTR + 16 + lane16] = f2bf(e1 * rs);
        L[rowloc * LSTR + 32 + lane16] = f2bf(e2 * rs);
        L[rowloc * LSTR + 48 + lane16] = f2bf(e3 * rs);
    }
    __threadfence_block();   // drain pa writes (wave-private LDS; no s_barrier)

    f32x4 acc[12];
#pragma unroll
    for (int nt = 0; nt < 12; nt++) acc[nt] = (f32x4){0.f, 0.f, 0.f, 0.f};
#pragma unroll
    for (int kt = 0; kt < 2; kt++) {
        bf16x8 a = *reinterpret_cast<const bf16x8*>(L + lane16 * LSTR + kt * 32 + quad * 8);
#pragma unroll
        for (int nt = 0; nt < 12; nt++) {
            bf16x8 bfr = *reinterpret_cast<const bf16x8*>(B2 + ((size_t)(kt * 12 + nt) * 64 + lane) * 8);
            acc[nt] = __builtin_amdgcn_mfma_f32_16x16x32_bf16(a, bfr, acc[nt], 0, 0, 0);
        }
    }
    __threadfence_block();   // pa reads complete before pf overwrites rows
#pragma unroll
    for (int nt = 0; nt < 12; nt++) {
#pragma unroll
        for (int r = 0; r < 4; r++) {
            int rowloc = quad * 4 + r;
            L[rowloc * LSTR + nt * 16 + lane16] = f2bf(oreg[nt][r] - acc[nt][r]);
        }
    }
    __threadfence_block();   // drain pf writes

#pragma unroll
    for (int nt = 0; nt < 12; nt++) acc[nt] = (f32x4){0.f, 0.f, 0.f, 0.f};
#pragma unroll
    for (int kt = 0; kt < 6; kt++) {
        bf16x8 a = *reinterpret_cast<const bf16x8*>(L + lane16 * LSTR + kt * 32 + quad * 8);
#pragma unroll
        for (int nt = 0; nt < 12; nt++) {
            bf16x8 bfr = *reinterpret_cast<const bf16x8*>(B3 + ((size_t)(kt * 12 + nt) * 64 + lane) * 8);
            acc[nt] = __builtin_amdgcn_mfma_f32_16x16x32_bf16(a, bfr, acc[nt], 0, 0, 0);
        }
    }

#pragma unroll
    for (int nt = 0; nt < 12; nt++) {
        float bias = gate_b[nt * 16 + lane16];
#pragma unroll
        for (int r = 0; r < 4; r++) {
            int rowloc = quad * 4 + r;
            size_t idx = (size_t)(row0 + rowloc) * FEATD + nt * 16 + lane16;
            float z = acc[nt][r] + bias;
            float g = 1.f / (1.f + __expf(-z));
            float pf = bf2f(L[rowloc * LSTR + nt * 16 + lane16]);
            dout[idx] = pf + g * (oreg[nt][r] - pf);
        }
    }
}

extern "C" void kernel_launch(void* const* d_in, const int* in_sizes, int n_in,
                              void* d_out, int out_size, void* d_ws, size_t ws_size,
                              hipStream_t stream) {
    (void)in_sizes; (void)n_in; (void)out_size; (void)ws_size;
    const float* features = (const float*)d_in[0];
    const float* rel_emb  = (const float*)d_in[1];
    const float* proxy    = (const float*)d_in[2];
    const float* gate_w   = (const float*)d_in[3];
    const float* gate_b   = (const float*)d_in[4];
    const float* attn_k   = (const float*)d_in[5];
    const int*   adj      = (const int*)d_in[6];
    const int*   r_index  = (const int*)d_in[7];
    // d_in[8] (r_val) unused: positive scale cancels under l2norm; r_index[0]==arange(E).

    unsigned short* fin0 = (unsigned short*)d_ws;           // N*64 bf16
    unsigned short* fin1 = fin0 + (size_t)N_NODES * 64;     // N*64 bf16
    unsigned short* fin2 = fin1 + (size_t)N_NODES * 64;     // N*64 bf16
    float* reln    = (float*)(fin2 + (size_t)N_NODES * 64); // 500*64 fp32
    float* expdot  = reln + RSZ * 64;                       // 2*500
    float* pninv   = expdot + 2 * RSZ;                      // 64
    unsigned short* B1 = (unsigned short*)(pninv + 64);     // 12288
    unsigned short* B2 = B1 + 12288;                        // 12288
    unsigned short* B3 = B2 + 12288;                        // 36864
    unsigned int* pedge = (unsigned int*)(B3 + 36864);      // NEDGE u32

    const int* src = adj + NEDGE;       // adj[1]
    const int* rel = r_index + NEDGE;   // r_index[1]

    k_prep  <<<dim3(4693), dim3(256), 0, stream>>>(features, rel_emb, attn_k, proxy, gate_w,
                                                   src, rel, fin0, reln, expdot,
                                                   pninv, B1, B2, B3, pedge);
    k_layer <<<dim3(LGRID), dim3(256), 0, stream>>>(pedge, reln, expdot,       fin0, fin1);
    k_layer <<<dim3(LGRID), dim3(256), 0, stream>>>(pedge, reln, expdot + RSZ, fin1, fin2);
    k_gate  <<<dim3(GGRID), dim3(256), 0, stream>>>(fin0, fin1, fin2, B1, B2, B3, pninv,
                                                    gate_b, (float*)d_out);
}